// Round 10
// baseline (1352.569 us; speedup 1.0000x reference)
//
#include <hip/hip_runtime.h>
#include <type_traits>

// ---------------------------------------------------------------------------
// CSAAttention — round 10.
//   Selection path: scalar fp64 FMA chains (bit-frozen since R4), retiled
//   32x64 for occupancy (1024 blocks vs 512). Bit-identical per-element
//   k-order chains -> absmax must stay exactly 0.00390625.
//   Value path: presplit packed bf16 hi/lo planes (split once per element),
//   MFMA GEMMs stage pure shorts. Bit-identical to R9's split-in-kernel.
//   Tier-B fallback (small ws): R9 value kernels verbatim.
// ---------------------------------------------------------------------------

#define DEVI __device__ __forceinline__

constexpr int Tn = 1024;
constexpr int Cn = 1024;
constexpr int Hn = 16;

typedef short bf16x8 __attribute__((ext_vector_type(8)));
typedef float f32x4 __attribute__((ext_vector_type(4)));

DEVI int wsumi(int v)   { for (int m = 1; m < 64; m <<= 1) v += __shfl_xor(v, m); return v; }
DEVI int wmini(int v)   { for (int m = 1; m < 64; m <<= 1) { int o = __shfl_xor(v, m); v = o < v ? o : v; } return v; }
DEVI float wfmax(float v){ for (int m = 1; m < 64; m <<= 1) v = fmaxf(v, __shfl_xor(v, m)); return v; }
DEVI float wfsum(float v){ for (int m = 1; m < 64; m <<= 1) v += __shfl_xor(v, m); return v; }

DEVI unsigned long long mapd(double x) {  // monotone fp64 -> uint64
  unsigned long long b = (unsigned long long)__double_as_longlong(x);
  return (b >> 63) ? ~b : (b | 0x8000000000000000ull);
}

DEVI unsigned short f2bf_rne(float x) {
  unsigned u = __float_as_uint(x);
  u += 0x7fffu + ((u >> 16) & 1u);
  return (unsigned short)(u >> 16);
}
struct BfPair { short hi, lo; };
DEVI BfPair split2(float x) {
  unsigned short h = f2bf_rne(x);
  float hf = __uint_as_float(((unsigned)h) << 16);
  BfPair r;
  r.hi = (short)h;
  r.lo = (short)f2bf_rne(x - hf);
  return r;
}
DEVI unsigned packbf(float x) {
  BfPair p = split2(x);
  return ((unsigned)(unsigned short)p.hi << 16) | (unsigned)(unsigned short)p.lo;
}
DEVI short uhi(unsigned u) { return (short)(u >> 16); }
DEVI short ulo(unsigned u) { return (short)(u & 0xffffu); }

// ---------------------------------------------------------------------------
// Selection-path scalar GEMM, retiled 32x64 (2x4 micro, 256 thr).
// Per-element fp64 FMA chain in ascending k (16-step tiles) — bit-identical
// to rounds 4-9. BTRANS: C=A*B^T. BIASMODE: 0 none, 1 bias[n], 2 bias[m].
// SIM: per-z (b,h) slices of Q/Kc, fp64 dot plane out.
// ---------------------------------------------------------------------------
template <typename OUTT, typename ACCT, bool BTRANS, int BIASMODE, bool SIM>
__global__ __launch_bounds__(256) void gemm32_k(
    const float* __restrict__ A, const float* __restrict__ B,
    const float* __restrict__ bias, OUTT* __restrict__ C,
    int Kd, int lda, int ldb, int ldc,
    long long zB, long long zC, int group_base)
{
  __shared__ float As[16][34];
  __shared__ float Bs[16][68];

  size_t offA = 0, offB, offC;
  if (SIM) {
    int pair = group_base + (int)blockIdx.z;
    int bb = pair >> 4, hh = pair & 15;
    offA = ((size_t)bb * Tn) * (size_t)lda + (size_t)hh * 64;
    offB = ((size_t)bb * Cn) * (size_t)ldb + (size_t)hh * 64;
    offC = (size_t)blockIdx.z * (size_t)Tn * (size_t)ldc;
  } else {
    offB = (size_t)blockIdx.z * (size_t)zB;
    offC = (size_t)blockIdx.z * (size_t)zC;
  }
  const float* Ab = A + offA;
  const float* Bb = B + offB;
  OUTT* Cb = C + offC;

  const int tid = threadIdx.x;
  const int tx = tid & 15, ty = tid >> 4;
  const int m0 = blockIdx.y * 32, n0 = blockIdx.x * 64;

  ACCT acc[2][4];
#pragma unroll
  for (int i = 0; i < 2; ++i)
#pragma unroll
    for (int j = 0; j < 4; ++j) acc[i][j] = (ACCT)0;

  for (int k0 = 0; k0 < Kd; k0 += 16) {
    if (tid < 128) {  // stage A: 32 rows x 16 k -> As[k][m]
      int m = tid >> 2, kf = tid & 3;
      float4 a = *(const float4*)(Ab + (size_t)(m0 + m) * lda + k0 + 4 * kf);
      As[4 * kf + 0][m] = a.x; As[4 * kf + 1][m] = a.y;
      As[4 * kf + 2][m] = a.z; As[4 * kf + 3][m] = a.w;
    }
    if (BTRANS) {     // stage B: 64 n-rows x 16 k -> Bs[k][n]
      int n = tid >> 2, kf = tid & 3;
      float4 b = *(const float4*)(Bb + (size_t)(n0 + n) * ldb + k0 + 4 * kf);
      Bs[4 * kf + 0][n] = b.x; Bs[4 * kf + 1][n] = b.y;
      Bs[4 * kf + 2][n] = b.z; Bs[4 * kf + 3][n] = b.w;
    } else {          // B[k][n]: 16 k-rows x 64 n
      int k = tid >> 4, nf = tid & 15;
      float4 b = *(const float4*)(Bb + (size_t)(k0 + k) * ldb + n0 + 4 * nf);
      *(float4*)&Bs[k][4 * nf] = b;
    }
    __syncthreads();
#pragma unroll
    for (int k = 0; k < 16; ++k) {
      float2 a2 = *(const float2*)&As[k][2 * ty];
      float4 b4 = *(const float4*)&Bs[k][4 * tx];
      float av[2] = {a2.x, a2.y};
      float bv[4] = {b4.x, b4.y, b4.z, b4.w};
#pragma unroll
      for (int i = 0; i < 2; ++i)
#pragma unroll
        for (int j = 0; j < 4; ++j)
          acc[i][j] += (ACCT)av[i] * (ACCT)bv[j];
    }
    __syncthreads();
  }

  if constexpr (std::is_same<OUTT, double>::value) {
#pragma unroll
    for (int i = 0; i < 2; ++i) {
      size_t m = (size_t)(m0 + 2 * ty + i);
      double* p = (double*)Cb + m * ldc + n0 + 4 * tx;
      p[0] = (double)acc[i][0]; p[1] = (double)acc[i][1];
      p[2] = (double)acc[i][2]; p[3] = (double)acc[i][3];
    }
  } else {
    float cbv[4] = {0.f, 0.f, 0.f, 0.f};
    if (BIASMODE == 1) {
      float4 b4 = *(const float4*)(bias + n0 + 4 * tx);
      cbv[0] = b4.x; cbv[1] = b4.y; cbv[2] = b4.z; cbv[3] = b4.w;
    }
#pragma unroll
    for (int i = 0; i < 2; ++i) {
      int m = m0 + 2 * ty + i;
      float rb = (BIASMODE == 2) ? bias[m] : 0.f;
      float4 s;
      s.x = (float)acc[i][0] + cbv[0] + rb;
      s.y = (float)acc[i][1] + cbv[1] + rb;
      s.z = (float)acc[i][2] + cbv[2] + rb;
      s.w = (float)acc[i][3] + cbv[3] + rb;
      *(float4*)((float*)Cb + (size_t)m * ldc + n0 + 4 * tx) = s;
    }
  }
}

// ---------------------------------------------------------------------------
// presplit: float plane -> packed (hi<<16|lo) bf16-split plane. n % 1024 == 0.
// ---------------------------------------------------------------------------
__global__ __launch_bounds__(256) void presplit_k(const float* __restrict__ src,
                                                  unsigned* __restrict__ dst, int n4)
{
  int stride = (int)gridDim.x * 256;
  for (int i = (int)blockIdx.x * 256 + (int)threadIdx.x; i < n4; i += stride) {
    float4 v = ((const float4*)src)[i];
    uint4 o;
    o.x = packbf(v.x); o.y = packbf(v.y); o.z = packbf(v.z); o.w = packbf(v.w);
    ((uint4*)dst)[i] = o;
  }
}

// ---------------------------------------------------------------------------
// Value-path MFMA GEMM on PRE-SPLIT packed operands. 64x64 tile, BK=32,
// 4 waves (wave 32x32, 2x2 frags). Same LDS/fragment/epilogue maps as the
// R9-validated kernel; only staging source differs (unpack, no split2).
// OUTPACK: write packed split (for Vf); else fp32.
// ---------------------------------------------------------------------------
template <bool BTRANS, int BIASMODE, bool OUTPACK>
__global__ __launch_bounds__(256) void mfma_ps_k(
    const unsigned* __restrict__ A, const unsigned* __restrict__ B,
    const float* __restrict__ bias, void* __restrict__ Cv,
    int Kd, int lda, int ldb, int ldc, long long zB, long long zC)
{
  __shared__ short Ah[4 * 64 * 8];
  __shared__ short Al[4 * 64 * 8];
  __shared__ short Bh[4 * 64 * 8];
  __shared__ short Bl[4 * 64 * 8];

  const unsigned* Bz = B + (size_t)blockIdx.z * (size_t)zB;

  const int tid = threadIdx.x;
  const int lane = tid & 63, w = tid >> 6;
  const int wr = w >> 1, wc = w & 1;
  const int m0 = blockIdx.y * 64, n0 = blockIdx.x * 64;
  const int r16 = lane & 15, kg = lane >> 4;

  f32x4 acc[2][2];
#pragma unroll
  for (int i = 0; i < 2; ++i)
#pragma unroll
    for (int j = 0; j < 2; ++j) acc[i][j] = (f32x4){0.f, 0.f, 0.f, 0.f};

  for (int k0 = 0; k0 < Kd; k0 += 32) {
    {  // stage A: row=tid>>2, 8 consecutive k (2x uint4)
      int row = tid >> 2, kseg = tid & 3;
      const unsigned* pa = A + (size_t)(m0 + row) * lda + k0 + kseg * 8;
      uint4 u0 = *(const uint4*)pa;
      uint4 u1 = *(const uint4*)(pa + 4);
      bf16x8 h = {uhi(u0.x), uhi(u0.y), uhi(u0.z), uhi(u0.w),
                  uhi(u1.x), uhi(u1.y), uhi(u1.z), uhi(u1.w)};
      bf16x8 l = {ulo(u0.x), ulo(u0.y), ulo(u0.z), ulo(u0.w),
                  ulo(u1.x), ulo(u1.y), ulo(u1.z), ulo(u1.w)};
      int idx = (kseg * 64 + row) * 8;
      *(bf16x8*)&Ah[idx] = h;
      *(bf16x8*)&Al[idx] = l;
    }
    if (BTRANS) {
      int row = tid >> 2, kseg = tid & 3;
      const unsigned* pb = Bz + (size_t)(n0 + row) * ldb + k0 + kseg * 8;
      uint4 u0 = *(const uint4*)pb;
      uint4 u1 = *(const uint4*)(pb + 4);
      bf16x8 h = {uhi(u0.x), uhi(u0.y), uhi(u0.z), uhi(u0.w),
                  uhi(u1.x), uhi(u1.y), uhi(u1.z), uhi(u1.w)};
      bf16x8 l = {ulo(u0.x), ulo(u0.y), ulo(u0.z), ulo(u0.w),
                  ulo(u1.x), ulo(u1.y), ulo(u1.z), ulo(u1.w)};
      int idx = (kseg * 64 + row) * 8;
      *(bf16x8*)&Bh[idx] = h;
      *(bf16x8*)&Bl[idx] = l;
    } else {  // B[k][n] column gather
      int col = tid & 63, kseg = tid >> 6;
      short hv[8], lv[8];
#pragma unroll
      for (int j = 0; j < 8; ++j) {
        unsigned u = Bz[(size_t)(k0 + kseg * 8 + j) * ldb + n0 + col];
        hv[j] = uhi(u); lv[j] = ulo(u);
      }
      bf16x8 h = {hv[0], hv[1], hv[2], hv[3], hv[4], hv[5], hv[6], hv[7]};
      bf16x8 l = {lv[0], lv[1], lv[2], lv[3], lv[4], lv[5], lv[6], lv[7]};
      int idx = (kseg * 64 + col) * 8;
      *(bf16x8*)&Bh[idx] = h;
      *(bf16x8*)&Bl[idx] = l;
    }
    __syncthreads();

    bf16x8 ah[2], al[2], bh[2], bl[2];
#pragma unroll
    for (int f = 0; f < 2; ++f) {
      int ia = (kg * 64 + wr * 32 + f * 16 + r16) * 8;
      int ib = (kg * 64 + wc * 32 + f * 16 + r16) * 8;
      ah[f] = *(const bf16x8*)&Ah[ia];
      al[f] = *(const bf16x8*)&Al[ia];
      bh[f] = *(const bf16x8*)&Bh[ib];
      bl[f] = *(const bf16x8*)&Bl[ib];
    }
#pragma unroll
    for (int fr = 0; fr < 2; ++fr)
#pragma unroll
      for (int fc = 0; fc < 2; ++fc) {
        f32x4 c = acc[fr][fc];
        c = __builtin_amdgcn_mfma_f32_16x16x32_bf16(al[fr], bh[fc], c, 0, 0, 0);
        c = __builtin_amdgcn_mfma_f32_16x16x32_bf16(ah[fr], bl[fc], c, 0, 0, 0);
        c = __builtin_amdgcn_mfma_f32_16x16x32_bf16(ah[fr], bh[fc], c, 0, 0, 0);
        acc[fr][fc] = c;
      }
    __syncthreads();
  }

#pragma unroll
  for (int fr = 0; fr < 2; ++fr)
#pragma unroll
    for (int fc = 0; fc < 2; ++fc) {
      int col = n0 + wc * 32 + fc * 16 + r16;
      float cb = (BIASMODE == 1) ? bias[col] : 0.f;
#pragma unroll
      for (int rr = 0; rr < 4; ++rr) {
        int row = m0 + wr * 32 + fr * 16 + kg * 4 + rr;
        float rb = (BIASMODE == 2) ? bias[row] : 0.f;
        float v = acc[fr][fc][rr] + cb + rb;
        size_t o = (size_t)row * ldc + col + (size_t)blockIdx.z * (size_t)zC;
        if (OUTPACK) ((unsigned*)Cv)[o] = packbf(v);
        else         ((float*)Cv)[o] = v;
      }
    }
}

// ---------------------------------------------------------------------------
// Value-path MFMA GEMM, split-in-kernel (R9-validated) — tier-B fallback.
// ---------------------------------------------------------------------------
template <bool BTRANS, int BIASMODE>
__global__ __launch_bounds__(256) void mfma_gemm_k(
    const float* __restrict__ A, const float* __restrict__ B,
    const float* __restrict__ bias, float* __restrict__ C,
    int Kd, int lda, int ldb, int ldc, long long zB, long long zC)
{
  __shared__ short Ah[4 * 64 * 8];
  __shared__ short Al[4 * 64 * 8];
  __shared__ short Bh[4 * 64 * 8];
  __shared__ short Bl[4 * 64 * 8];

  const float* Bz = B + (size_t)blockIdx.z * (size_t)zB;
  float* Cz = C + (size_t)blockIdx.z * (size_t)zC;

  const int tid = threadIdx.x;
  const int lane = tid & 63, w = tid >> 6;
  const int wr = w >> 1, wc = w & 1;
  const int m0 = blockIdx.y * 64, n0 = blockIdx.x * 64;
  const int r16 = lane & 15, kg = lane >> 4;

  f32x4 acc[2][2];
#pragma unroll
  for (int i = 0; i < 2; ++i)
#pragma unroll
    for (int j = 0; j < 2; ++j) acc[i][j] = (f32x4){0.f, 0.f, 0.f, 0.f};

  for (int k0 = 0; k0 < Kd; k0 += 32) {
    {
      int row = tid >> 2, kseg = tid & 3;
      const float* p = A + (size_t)(m0 + row) * lda + k0 + kseg * 8;
      float4 v0 = *(const float4*)p;
      float4 v1 = *(const float4*)(p + 4);
      BfPair q0 = split2(v0.x), q1 = split2(v0.y), q2 = split2(v0.z), q3 = split2(v0.w);
      BfPair q4 = split2(v1.x), q5 = split2(v1.y), q6 = split2(v1.z), q7 = split2(v1.w);
      bf16x8 h = {q0.hi, q1.hi, q2.hi, q3.hi, q4.hi, q5.hi, q6.hi, q7.hi};
      bf16x8 l = {q0.lo, q1.lo, q2.lo, q3.lo, q4.lo, q5.lo, q6.lo, q7.lo};
      int idx = (kseg * 64 + row) * 8;
      *(bf16x8*)&Ah[idx] = h;
      *(bf16x8*)&Al[idx] = l;
    }
    if (BTRANS) {
      int row = tid >> 2, kseg = tid & 3;
      const float* p = Bz + (size_t)(n0 + row) * ldb + k0 + kseg * 8;
      float4 v0 = *(const float4*)p;
      float4 v1 = *(const float4*)(p + 4);
      BfPair q0 = split2(v0.x), q1 = split2(v0.y), q2 = split2(v0.z), q3 = split2(v0.w);
      BfPair q4 = split2(v1.x), q5 = split2(v1.y), q6 = split2(v1.z), q7 = split2(v1.w);
      bf16x8 h = {q0.hi, q1.hi, q2.hi, q3.hi, q4.hi, q5.hi, q6.hi, q7.hi};
      bf16x8 l = {q0.lo, q1.lo, q2.lo, q3.lo, q4.lo, q5.lo, q6.lo, q7.lo};
      int idx = (kseg * 64 + row) * 8;
      *(bf16x8*)&Bh[idx] = h;
      *(bf16x8*)&Bl[idx] = l;
    } else {
      int col = tid & 63, kseg = tid >> 6;
      short hv[8], lv[8];
#pragma unroll
      for (int j = 0; j < 8; ++j) {
        BfPair p = split2(Bz[(size_t)(k0 + kseg * 8 + j) * ldb + n0 + col]);
        hv[j] = p.hi; lv[j] = p.lo;
      }
      bf16x8 h = {hv[0], hv[1], hv[2], hv[3], hv[4], hv[5], hv[6], hv[7]};
      bf16x8 l = {lv[0], lv[1], lv[2], lv[3], lv[4], lv[5], lv[6], lv[7]};
      int idx = (kseg * 64 + col) * 8;
      *(bf16x8*)&Bh[idx] = h;
      *(bf16x8*)&Bl[idx] = l;
    }
    __syncthreads();

    bf16x8 ah[2], al[2], bh[2], bl[2];
#pragma unroll
    for (int f = 0; f < 2; ++f) {
      int ia = (kg * 64 + wr * 32 + f * 16 + r16) * 8;
      int ib = (kg * 64 + wc * 32 + f * 16 + r16) * 8;
      ah[f] = *(const bf16x8*)&Ah[ia];
      al[f] = *(const bf16x8*)&Al[ia];
      bh[f] = *(const bf16x8*)&Bh[ib];
      bl[f] = *(const bf16x8*)&Bl[ib];
    }
#pragma unroll
    for (int fr = 0; fr < 2; ++fr)
#pragma unroll
      for (int fc = 0; fc < 2; ++fc) {
        f32x4 c = acc[fr][fc];
        c = __builtin_amdgcn_mfma_f32_16x16x32_bf16(al[fr], bh[fc], c, 0, 0, 0);
        c = __builtin_amdgcn_mfma_f32_16x16x32_bf16(ah[fr], bl[fc], c, 0, 0, 0);
        c = __builtin_amdgcn_mfma_f32_16x16x32_bf16(ah[fr], bh[fc], c, 0, 0, 0);
        acc[fr][fc] = c;
      }
    __syncthreads();
  }

#pragma unroll
  for (int fr = 0; fr < 2; ++fr)
#pragma unroll
    for (int fc = 0; fc < 2; ++fc) {
      int col = n0 + wc * 32 + fc * 16 + r16;
      float cb = (BIASMODE == 1) ? bias[col] : 0.f;
#pragma unroll
      for (int rr = 0; rr < 4; ++rr) {
        int row = m0 + wr * 32 + fr * 16 + kg * 4 + rr;
        float rb = (BIASMODE == 2) ? bias[row] : 0.f;
        Cz[(size_t)row * ldc + col] = acc[fr][fc][rr] + cb + rb;
      }
    }
}

// kn[b*16+h][c] = 1 / max(||Kc[b, c, h*64 : +64]||, 1e-12)   (fp64)
__global__ __launch_bounds__(256) void kn_k2(const float* __restrict__ Kc,
                                             double* __restrict__ kn)
{
  int idx = (int)blockIdx.x * 256 + (int)threadIdx.x;
  int c = idx & 1023;
  int p = idx >> 10;
  int b = p >> 4, h = p & 15;
  const float* row = Kc + ((size_t)(b * 1024 + c)) * 1024 + h * 64;
  double s = 0.0;
  for (int d = 0; d < 64; ++d) { double v = (double)row[d]; s += v * v; }
  kn[(size_t)p * 1024 + c] = 1.0 / fmax(sqrt(s), 1e-12);
}

// Fused exact top-64 + softmax + PV (bit-frozen). PACK: at written as
// packed bf16-split (tier-A, for Wo GEMM); else fp32.
template <bool PACK>
__global__ __launch_bounds__(256) void topk_attn_k(
    const double* __restrict__ dotb, const double* __restrict__ kn,
    const float* __restrict__ Vc, void* __restrict__ atOut, int group_base)
{
  __shared__ int sC[4][64];
  __shared__ float sD[4][64];

  const int lane = threadIdx.x & 63, wv = threadIdx.x >> 6;
  const int g = (int)blockIdx.x >> 8;
  const int t = ((int)blockIdx.x & 255) * 4 + wv;
  const int pair = group_base + g;
  const int bb = pair >> 4, hh = pair & 15;

  const double* drow = dotb + ((size_t)g * Tn + t) * (size_t)Cn;
  const double* knr  = kn + ((size_t)(bb * Hn + hh)) * Cn;

  double dv[16];
  unsigned long long u[16];
#pragma unroll
  for (int j = 0; j < 8; ++j) {
    double2 dd = *(const double2*)(drow + j * 128 + 2 * lane);
    double2 kk = *(const double2*)(knr  + j * 128 + 2 * lane);
    dv[2 * j] = dd.x; dv[2 * j + 1] = dd.y;
    u[2 * j]     = mapd(dd.x * kk.x);
    u[2 * j + 1] = mapd(dd.y * kk.y);
  }
  unsigned hi[16];
#pragma unroll
  for (int i = 0; i < 16; ++i) hi[i] = (unsigned)(u[i] >> 32);

  unsigned TH = 0;
  for (int bit = 31; bit >= 0; --bit) {
    unsigned Tc = TH | (1u << bit);
    int c = 0;
#pragma unroll
    for (int i = 0; i < 16; ++i) c += (hi[i] >= Tc);
    if (wsumi(c) >= 64) TH = Tc;
  }
  int mhi = 0;
#pragma unroll
  for (int i = 0; i < 16; ++i) mhi += (hi[i] > TH);
  mhi = wsumi(mhi);
  const int need1 = 64 - mhi;
  unsigned TL = 0;
  for (int bit = 31; bit >= 0; --bit) {
    unsigned Tc = TL | (1u << bit);
    int c = 0;
#pragma unroll
    for (int i = 0; i < 16; ++i) c += (hi[i] == TH && (unsigned)u[i] >= Tc);
    if (wsumi(c) >= need1) TL = Tc;
  }
  const unsigned long long V64 = ((unsigned long long)TH << 32) | TL;

  int base = 0;
#pragma unroll
  for (int i = 0; i < 16; ++i) {
    const int cix = 128 * (i >> 1) + 2 * lane + (i & 1);
    bool sel = (u[i] > V64);
    unsigned long long mk = __ballot(sel);
    if (sel) {
      int r = __popcll(mk & ((1ull << lane) - 1ull));
      sC[wv][base + r] = cix;
      sD[wv][base + r] = (float)dv[i];
    }
    base += __popcll(mk);
  }
  const int need = 64 - base;
  unsigned taken = 0;
  for (int r = 0; r < need; ++r) {
    int mn = 0x7fffffff;
#pragma unroll
    for (int i = 0; i < 16; ++i) {
      int cix = 128 * (i >> 1) + 2 * lane + (i & 1);
      if (u[i] == V64 && !((taken >> i) & 1u)) mn = mn < cix ? mn : cix;
    }
    mn = wmini(mn);
#pragma unroll
    for (int i = 0; i < 16; ++i) {
      int cix = 128 * (i >> 1) + 2 * lane + (i & 1);
      if (u[i] == V64 && !((taken >> i) & 1u) && cix == mn) {
        taken |= 1u << i;
        sC[wv][base + r] = mn;
        sD[wv][base + r] = (float)dv[i];
      }
    }
  }
  __syncthreads();

  int ck = sC[wv][lane];
  float sc = sD[wv][lane] * 0.125f;
  float mx = wfmax(sc);
  float w = expf(sc - mx);
  float sw = wfsum(w);
  w /= sw;

  const float* Vb = Vc + (size_t)bb * ((size_t)Cn * 1024) + hh * 64 + lane;
  float acc = 0.f;
#pragma unroll 4
  for (int k = 0; k < 64; ++k) {
    int c = __shfl(ck, k);
    float wk = __shfl(w, k);
    acc = fmaf(wk, Vb[(size_t)c * 1024], acc);
  }
  size_t o = ((size_t)(bb * Tn + t)) * 1024 + hh * 64 + lane;
  if (PACK) ((unsigned*)atOut)[o] = packbf(acc);
  else      ((float*)atOut)[o] = acc;
}

// ---------------------------------------------------------------------------
extern "C" void kernel_launch(void* const* d_in, const int* in_sizes, int n_in,
                              void* d_out, int out_size, void* d_ws, size_t ws_size,
                              hipStream_t stream)
{
  const float* x  = (const float*)d_in[0];
  const float* Wq = (const float*)d_in[1];
  const float* bq = (const float*)d_in[2];
  const float* Wk = (const float*)d_in[3];
  const float* bk = (const float*)d_in[4];
  const float* Wv = (const float*)d_in[5];
  const float* bv = (const float*)d_in[6];
  const float* Wo = (const float*)d_in[7];
  const float* bo = (const float*)d_in[8];
  const float* Wc = (const float*)d_in[9];
  const float* bc = (const float*)d_in[10];
  float* out = (float*)d_out;

  const size_t NE = (size_t)2048 * 1024;
  float* Q   = (float*)d_ws;            // [0, 8MiB)
  float* Kf  = Q + NE;                  // [8, 16): fp32 K, later dot planes
  float* Vf  = Kf + NE;                 // [16,24): Vf fp32 (B) / Vfs packed (A)
  float* Kc  = Vf + NE;                 // [24,32)
  float* Vc  = Kc + NE;                 // [32,40)
  float* at  = Vc + NE;                 // [40,48): xs->ats (A) / at fp32 (B)
  double* kn = (double*)(at + NE);      // 256KiB
  unsigned* Wspl = (unsigned*)(kn + 32768);  // 4MiB weight-split region (A)

  unsigned* xs_ats = (unsigned*)at;     // packed planes share the at slot
  unsigned* Vfs    = (unsigned*)Vf;
  double* dotp = (double*)Kf;           // 16MiB (Kf+Vf dead) -> G=2 always

  const size_t fixedB = 6 * NE * 4 + 32768 * 8;
  if (ws_size < fixedB) return;
  const bool TA = ws_size >= fixedB + ((size_t)1 << 22);  // +4MiB tier

  dim3 blk(256, 1, 1);
  const long long M1 = 1024 * 1024;

  // Selection-path projections (retiled scalar fp64; bit-identical chains)
  gemm32_k<float, double, true, 1, false><<<dim3(16, 64, 1), blk, 0, stream>>>(
      x, Wq, bq, Q, 1024, 1024, 1024, 1024, 0, 0, 0);
  gemm32_k<float, double, true, 1, false><<<dim3(16, 64, 1), blk, 0, stream>>>(
      x, Wk, bk, Kf, 1024, 1024, 1024, 1024, 0, 0, 0);

  if (TA) {
    presplit_k<<<dim3(512), blk, 0, stream>>>(x, xs_ats, (int)(NE / 4));
    presplit_k<<<dim3(512), blk, 0, stream>>>(Wv, Wspl, (int)(M1 / 4));
    mfma_ps_k<true, 1, true><<<dim3(16, 32, 1), blk, 0, stream>>>(
        xs_ats, Wspl, bv, Vfs, 1024, 1024, 1024, 1024, 0, 0);
  } else {
    mfma_gemm_k<true, 1><<<dim3(16, 32, 1), blk, 0, stream>>>(
        x, Wv, bv, Vf, 1024, 1024, 1024, 1024, 0, 0);
  }

  // Compress: Kc scalar fp64 (bit-frozen); Vc MFMA
  gemm32_k<float, double, false, 2, false><<<dim3(16, 32, 2), blk, 0, stream>>>(
      Wc, Kf, bc, Kc, 1024, 1024, 1024, 1024, M1, M1, 0);
  if (TA) {
    presplit_k<<<dim3(512), blk, 0, stream>>>(Wc, Wspl, (int)(M1 / 4));
    mfma_ps_k<false, 2, false><<<dim3(16, 16, 2), blk, 0, stream>>>(
        Wspl, Vfs, bc, Vc, 1024, 1024, 1024, 1024, M1, M1);
  } else {
    mfma_gemm_k<false, 2><<<dim3(16, 16, 2), blk, 0, stream>>>(
        Wc, Vf, bc, Vc, 1024, 1024, 1024, 1024, M1, M1);
  }

  kn_k2<<<dim3(128), blk, 0, stream>>>(Kc, kn);

  // Dots (retiled SIM fp64) + fused topk/softmax/PV, G=2 in dead Kf+Vf
  for (int gb = 0; gb < 32; gb += 2) {
    gemm32_k<double, double, true, 0, true><<<dim3(16, 32, 2), blk, 0, stream>>>(
        Q, Kc, nullptr, dotp, 64, 1024, 1024, 1024, 0, 0, gb);
    if (TA)
      topk_attn_k<true><<<dim3(512), blk, 0, stream>>>(dotp, kn, Vc, xs_ats, gb);
    else
      topk_attn_k<false><<<dim3(512), blk, 0, stream>>>(dotp, kn, Vc, at, gb);
  }

  // Output projection
  if (TA) {
    presplit_k<<<dim3(512), blk, 0, stream>>>(Wo, Wspl, (int)(M1 / 4));
    mfma_ps_k<true, 1, false><<<dim3(16, 32, 1), blk, 0, stream>>>(
        xs_ats, Wspl, bo, out, 1024, 1024, 1024, 1024, 0, 0);
  } else {
    mfma_gemm_k<true, 1><<<dim3(16, 32, 1), blk, 0, stream>>>(
        at, Wo, bo, out, 1024, 1024, 1024, 1024, 0, 0);
  }
}

// Round 11
// 960.815 us; speedup vs baseline: 1.4077x; 1.4077x over previous
//
#include <hip/hip_runtime.h>
#include <type_traits>

// ---------------------------------------------------------------------------
// CSAAttention — round 11 = round 9 + ONE change: value-path presplit to
// separate bf16 hi/lo planes; V-proj & Wo use pure-bf16-staging MFMA GEMM
// (no split2 in the hot loop). All pipeline values bit-identical to R9.
// Selection path (fp64 scalar GEMMs, radix top-64): R9 verbatim, frozen.
// ---------------------------------------------------------------------------

#define DEVI __device__ __forceinline__

constexpr int Tn = 1024;
constexpr int Cn = 1024;
constexpr int Hn = 16;

typedef short bf16x8 __attribute__((ext_vector_type(8)));
typedef float f32x4 __attribute__((ext_vector_type(4)));

DEVI int wsumi(int v)   { for (int m = 1; m < 64; m <<= 1) v += __shfl_xor(v, m); return v; }
DEVI int wmini(int v)   { for (int m = 1; m < 64; m <<= 1) { int o = __shfl_xor(v, m); v = o < v ? o : v; } return v; }
DEVI float wfmax(float v){ for (int m = 1; m < 64; m <<= 1) v = fmaxf(v, __shfl_xor(v, m)); return v; }
DEVI float wfsum(float v){ for (int m = 1; m < 64; m <<= 1) v += __shfl_xor(v, m); return v; }

DEVI unsigned long long mapd(double x) {  // monotone fp64 -> uint64
  unsigned long long b = (unsigned long long)__double_as_longlong(x);
  return (b >> 63) ? ~b : (b | 0x8000000000000000ull);
}

DEVI unsigned short f2bf_rne(float x) {
  unsigned u = __float_as_uint(x);
  u += 0x7fffu + ((u >> 16) & 1u);
  return (unsigned short)(u >> 16);
}
struct BfPair { short hi, lo; };
DEVI BfPair split2(float x) {
  unsigned short h = f2bf_rne(x);
  float hf = __uint_as_float(((unsigned)h) << 16);
  BfPair r;
  r.hi = (short)h;
  r.lo = (short)f2bf_rne(x - hf);
  return r;
}

// ---------------------------------------------------------------------------
// Selection-path tiled GEMM (validated R4-R9; numerics frozen).
// ---------------------------------------------------------------------------
template <typename OUTT, typename ACCT, bool BTRANS, int BIASMODE, bool SIM>
__global__ __launch_bounds__(256) void gemm_k(
    const float* __restrict__ A, const float* __restrict__ B,
    const float* __restrict__ bias, OUTT* __restrict__ C,
    int Kd, int lda, int ldb, int ldc,
    long long zA, long long zB, long long zC, int group_base)
{
  __shared__ float As[16][68];
  __shared__ float Bs[16][68];

  size_t offA, offB, offC;
  if (SIM) {
    int pair = group_base + (int)blockIdx.z;
    int bb = pair >> 4, hh = pair & 15;
    offA = ((size_t)bb * Tn) * (size_t)lda + (size_t)hh * 64;
    offB = ((size_t)bb * Cn) * (size_t)ldb + (size_t)hh * 64;
    offC = (size_t)blockIdx.z * (size_t)Tn * (size_t)ldc;
  } else {
    offA = (size_t)blockIdx.z * (size_t)zA;
    offB = (size_t)blockIdx.z * (size_t)zB;
    offC = (size_t)blockIdx.z * (size_t)zC;
  }
  const float* Ab = A + offA;
  const float* Bb = B + offB;
  OUTT* Cb = C + offC;

  const int tid = threadIdx.x;
  const int tx = tid & 15, ty = tid >> 4;
  const int m0 = blockIdx.y * 64, n0 = blockIdx.x * 64;

  ACCT acc[4][4];
#pragma unroll
  for (int i = 0; i < 4; ++i)
#pragma unroll
    for (int j = 0; j < 4; ++j) acc[i][j] = (ACCT)0;

  for (int k0 = 0; k0 < Kd; k0 += 16) {
    {
      int m = tid >> 2, kf = tid & 3;
      float4 a = *(const float4*)(Ab + (size_t)(m0 + m) * lda + k0 + 4 * kf);
      As[4 * kf + 0][m] = a.x; As[4 * kf + 1][m] = a.y;
      As[4 * kf + 2][m] = a.z; As[4 * kf + 3][m] = a.w;
    }
    if (BTRANS) {
      int n = tid >> 2, kf = tid & 3;
      float4 b = *(const float4*)(Bb + (size_t)(n0 + n) * ldb + k0 + 4 * kf);
      Bs[4 * kf + 0][n] = b.x; Bs[4 * kf + 1][n] = b.y;
      Bs[4 * kf + 2][n] = b.z; Bs[4 * kf + 3][n] = b.w;
    } else {
      int k = tid >> 4, nf = tid & 15;
      float4 b = *(const float4*)(Bb + (size_t)(k0 + k) * ldb + n0 + 4 * nf);
      *(float4*)&Bs[k][4 * nf] = b;
    }
    __syncthreads();
#pragma unroll
    for (int k = 0; k < 16; ++k) {
      float4 a4 = *(const float4*)&As[k][4 * ty];
      float4 b4 = *(const float4*)&Bs[k][4 * tx];
      float av[4] = {a4.x, a4.y, a4.z, a4.w};
      float bv[4] = {b4.x, b4.y, b4.z, b4.w};
#pragma unroll
      for (int i = 0; i < 4; ++i)
#pragma unroll
        for (int j = 0; j < 4; ++j)
          acc[i][j] += (ACCT)av[i] * (ACCT)bv[j];
    }
    __syncthreads();
  }

  if constexpr (std::is_same<OUTT, double>::value) {
#pragma unroll
    for (int i = 0; i < 4; ++i) {
      size_t m = (size_t)(m0 + 4 * ty + i);
      double* p = (double*)Cb + m * ldc + n0 + 4 * tx;
      p[0] = (double)acc[i][0]; p[1] = (double)acc[i][1];
      p[2] = (double)acc[i][2]; p[3] = (double)acc[i][3];
    }
  } else {
    float cbv[4] = {0.f, 0.f, 0.f, 0.f};
    if (BIASMODE == 1) {
      float4 b4 = *(const float4*)(bias + n0 + 4 * tx);
      cbv[0] = b4.x; cbv[1] = b4.y; cbv[2] = b4.z; cbv[3] = b4.w;
    }
#pragma unroll
    for (int i = 0; i < 4; ++i) {
      int m = m0 + 4 * ty + i;
      float rb = (BIASMODE == 2) ? bias[m] : 0.f;
      float4 s;
      s.x = (float)acc[i][0] + cbv[0] + rb;
      s.y = (float)acc[i][1] + cbv[1] + rb;
      s.z = (float)acc[i][2] + cbv[2] + rb;
      s.w = (float)acc[i][3] + cbv[3] + rb;
      *(float4*)((float*)Cb + (size_t)m * ldc + n0 + 4 * tx) = s;
    }
  }
}

// ---------------------------------------------------------------------------
// presplit2: fp32 plane -> two separate bf16 planes (hi, lo). n8 = n/8.
// ---------------------------------------------------------------------------
__global__ __launch_bounds__(256) void presplit2_k(
    const float* __restrict__ src, short* __restrict__ hi,
    short* __restrict__ lo, int n8)
{
  int stride = (int)gridDim.x * 256;
  for (int i = (int)blockIdx.x * 256 + (int)threadIdx.x; i < n8; i += stride) {
    float4 v0 = ((const float4*)src)[2 * i];
    float4 v1 = ((const float4*)src)[2 * i + 1];
    BfPair q0 = split2(v0.x), q1 = split2(v0.y), q2 = split2(v0.z), q3 = split2(v0.w);
    BfPair q4 = split2(v1.x), q5 = split2(v1.y), q6 = split2(v1.z), q7 = split2(v1.w);
    bf16x8 h = {q0.hi, q1.hi, q2.hi, q3.hi, q4.hi, q5.hi, q6.hi, q7.hi};
    bf16x8 l = {q0.lo, q1.lo, q2.lo, q3.lo, q4.lo, q5.lo, q6.lo, q7.lo};
    ((bf16x8*)hi)[i] = h;
    ((bf16x8*)lo)[i] = l;
  }
}

// ---------------------------------------------------------------------------
// Pure-bf16-staging MFMA GEMM: C = A * B^T + bias[n], fp32 out.
// A from (Ahi, Alo) [M][K] bf16 planes; B from (Bhi, Blo) [N][K].
// 64x64 tile, BK=32, 4 waves (wave 32x32, 2x2 frags). Fragment/epilogue
// maps identical to the R9-validated mfma_gemm_k; staging has ZERO VALU.
// ---------------------------------------------------------------------------
__global__ __launch_bounds__(256) void bfgemm_k(
    const short* __restrict__ Ahi, const short* __restrict__ Alo,
    const short* __restrict__ Bhi, const short* __restrict__ Blo,
    const float* __restrict__ bias, float* __restrict__ C,
    int Kd, int lda, int ldb, int ldc)
{
  __shared__ short Ah[4 * 64 * 8];
  __shared__ short Al[4 * 64 * 8];
  __shared__ short Bh[4 * 64 * 8];
  __shared__ short Bl[4 * 64 * 8];

  const int tid = threadIdx.x;
  const int lane = tid & 63, w = tid >> 6;
  const int wr = w >> 1, wc = w & 1;
  const int m0 = blockIdx.y * 64, n0 = blockIdx.x * 64;
  const int r16 = lane & 15, kg = lane >> 4;

  f32x4 acc[2][2];
#pragma unroll
  for (int i = 0; i < 2; ++i)
#pragma unroll
    for (int j = 0; j < 2; ++j) acc[i][j] = (f32x4){0.f, 0.f, 0.f, 0.f};

  const int row = tid >> 2, kseg = tid & 3;
  const int sidx = (kseg * 64 + row) * 8;

  for (int k0 = 0; k0 < Kd; k0 += 32) {
    size_t ao = (size_t)(m0 + row) * lda + k0 + kseg * 8;
    size_t bo = (size_t)(n0 + row) * ldb + k0 + kseg * 8;
    *(bf16x8*)&Ah[sidx] = *(const bf16x8*)(Ahi + ao);
    *(bf16x8*)&Al[sidx] = *(const bf16x8*)(Alo + ao);
    *(bf16x8*)&Bh[sidx] = *(const bf16x8*)(Bhi + bo);
    *(bf16x8*)&Bl[sidx] = *(const bf16x8*)(Blo + bo);
    __syncthreads();

    bf16x8 ah[2], al[2], bh[2], bl[2];
#pragma unroll
    for (int f = 0; f < 2; ++f) {
      int ia = (kg * 64 + wr * 32 + f * 16 + r16) * 8;
      int ib = (kg * 64 + wc * 32 + f * 16 + r16) * 8;
      ah[f] = *(const bf16x8*)&Ah[ia];
      al[f] = *(const bf16x8*)&Al[ia];
      bh[f] = *(const bf16x8*)&Bh[ib];
      bl[f] = *(const bf16x8*)&Bl[ib];
    }
#pragma unroll
    for (int fr = 0; fr < 2; ++fr)
#pragma unroll
      for (int fc = 0; fc < 2; ++fc) {
        f32x4 c = acc[fr][fc];
        c = __builtin_amdgcn_mfma_f32_16x16x32_bf16(al[fr], bh[fc], c, 0, 0, 0);
        c = __builtin_amdgcn_mfma_f32_16x16x32_bf16(ah[fr], bl[fc], c, 0, 0, 0);
        c = __builtin_amdgcn_mfma_f32_16x16x32_bf16(ah[fr], bh[fc], c, 0, 0, 0);
        acc[fr][fc] = c;
      }
    __syncthreads();
  }

#pragma unroll
  for (int fr = 0; fr < 2; ++fr)
#pragma unroll
    for (int fc = 0; fc < 2; ++fc) {
      int col = n0 + wc * 32 + fc * 16 + r16;
      float cb = bias[col];
#pragma unroll
      for (int rr = 0; rr < 4; ++rr) {
        int rw = m0 + wr * 32 + fr * 16 + kg * 4 + rr;
        C[(size_t)rw * ldc + col] = acc[fr][fc][rr] + cb;
      }
    }
}

// ---------------------------------------------------------------------------
// Value-path MFMA GEMM, split-in-kernel (R9-validated) — used for Vc and
// as the full tier-B fallback.
// ---------------------------------------------------------------------------
template <bool BTRANS, int BIASMODE>
__global__ __launch_bounds__(256) void mfma_gemm_k(
    const float* __restrict__ A, const float* __restrict__ B,
    const float* __restrict__ bias, float* __restrict__ C,
    int Kd, int lda, int ldb, int ldc, long long zB, long long zC)
{
  __shared__ short Ah[4 * 64 * 8];
  __shared__ short Al[4 * 64 * 8];
  __shared__ short Bh[4 * 64 * 8];
  __shared__ short Bl[4 * 64 * 8];

  const float* Bz = B + (size_t)blockIdx.z * (size_t)zB;
  float* Cz = C + (size_t)blockIdx.z * (size_t)zC;

  const int tid = threadIdx.x;
  const int lane = tid & 63, w = tid >> 6;
  const int wr = w >> 1, wc = w & 1;
  const int m0 = blockIdx.y * 64, n0 = blockIdx.x * 64;
  const int r16 = lane & 15, kg = lane >> 4;

  f32x4 acc[2][2];
#pragma unroll
  for (int i = 0; i < 2; ++i)
#pragma unroll
    for (int j = 0; j < 2; ++j) acc[i][j] = (f32x4){0.f, 0.f, 0.f, 0.f};

  for (int k0 = 0; k0 < Kd; k0 += 32) {
    {
      int row = tid >> 2, kseg = tid & 3;
      const float* p = A + (size_t)(m0 + row) * lda + k0 + kseg * 8;
      float4 v0 = *(const float4*)p;
      float4 v1 = *(const float4*)(p + 4);
      BfPair q0 = split2(v0.x), q1 = split2(v0.y), q2 = split2(v0.z), q3 = split2(v0.w);
      BfPair q4 = split2(v1.x), q5 = split2(v1.y), q6 = split2(v1.z), q7 = split2(v1.w);
      bf16x8 h = {q0.hi, q1.hi, q2.hi, q3.hi, q4.hi, q5.hi, q6.hi, q7.hi};
      bf16x8 l = {q0.lo, q1.lo, q2.lo, q3.lo, q4.lo, q5.lo, q6.lo, q7.lo};
      int idx = (kseg * 64 + row) * 8;
      *(bf16x8*)&Ah[idx] = h;
      *(bf16x8*)&Al[idx] = l;
    }
    if (BTRANS) {
      int row = tid >> 2, kseg = tid & 3;
      const float* p = Bz + (size_t)(n0 + row) * ldb + k0 + kseg * 8;
      float4 v0 = *(const float4*)p;
      float4 v1 = *(const float4*)(p + 4);
      BfPair q0 = split2(v0.x), q1 = split2(v0.y), q2 = split2(v0.z), q3 = split2(v0.w);
      BfPair q4 = split2(v1.x), q5 = split2(v1.y), q6 = split2(v1.z), q7 = split2(v1.w);
      bf16x8 h = {q0.hi, q1.hi, q2.hi, q3.hi, q4.hi, q5.hi, q6.hi, q7.hi};
      bf16x8 l = {q0.lo, q1.lo, q2.lo, q3.lo, q4.lo, q5.lo, q6.lo, q7.lo};
      int idx = (kseg * 64 + row) * 8;
      *(bf16x8*)&Bh[idx] = h;
      *(bf16x8*)&Bl[idx] = l;
    } else {
      int col = tid & 63, kseg = tid >> 6;
      short hv[8], lv[8];
#pragma unroll
      for (int j = 0; j < 8; ++j) {
        BfPair p = split2(Bz[(size_t)(k0 + kseg * 8 + j) * ldb + n0 + col]);
        hv[j] = p.hi; lv[j] = p.lo;
      }
      bf16x8 h = {hv[0], hv[1], hv[2], hv[3], hv[4], hv[5], hv[6], hv[7]};
      bf16x8 l = {lv[0], lv[1], lv[2], lv[3], lv[4], lv[5], lv[6], lv[7]};
      int idx = (kseg * 64 + col) * 8;
      *(bf16x8*)&Bh[idx] = h;
      *(bf16x8*)&Bl[idx] = l;
    }
    __syncthreads();

    bf16x8 ah[2], al[2], bh[2], bl[2];
#pragma unroll
    for (int f = 0; f < 2; ++f) {
      int ia = (kg * 64 + wr * 32 + f * 16 + r16) * 8;
      int ib = (kg * 64 + wc * 32 + f * 16 + r16) * 8;
      ah[f] = *(const bf16x8*)&Ah[ia];
      al[f] = *(const bf16x8*)&Al[ia];
      bh[f] = *(const bf16x8*)&Bh[ib];
      bl[f] = *(const bf16x8*)&Bl[ib];
    }
#pragma unroll
    for (int fr = 0; fr < 2; ++fr)
#pragma unroll
      for (int fc = 0; fc < 2; ++fc) {
        f32x4 c = acc[fr][fc];
        c = __builtin_amdgcn_mfma_f32_16x16x32_bf16(al[fr], bh[fc], c, 0, 0, 0);
        c = __builtin_amdgcn_mfma_f32_16x16x32_bf16(ah[fr], bl[fc], c, 0, 0, 0);
        c = __builtin_amdgcn_mfma_f32_16x16x32_bf16(ah[fr], bh[fc], c, 0, 0, 0);
        acc[fr][fc] = c;
      }
    __syncthreads();
  }

#pragma unroll
  for (int fr = 0; fr < 2; ++fr)
#pragma unroll
    for (int fc = 0; fc < 2; ++fc) {
      int col = n0 + wc * 32 + fc * 16 + r16;
      float cb = (BIASMODE == 1) ? bias[col] : 0.f;
#pragma unroll
      for (int rr = 0; rr < 4; ++rr) {
        int rw = m0 + wr * 32 + fr * 16 + kg * 4 + rr;
        float rb = (BIASMODE == 2) ? bias[rw] : 0.f;
        Cz[(size_t)rw * ldc + col] = acc[fr][fc][rr] + cb + rb;
      }
    }
}

// kn[b*16+h][c] = 1 / max(||Kc[b, c, h*64 : +64]||, 1e-12)   (fp64)
__global__ __launch_bounds__(256) void kn_k2(const float* __restrict__ Kc,
                                             double* __restrict__ kn)
{
  int idx = (int)blockIdx.x * 256 + (int)threadIdx.x;
  int c = idx & 1023;
  int p = idx >> 10;
  int b = p >> 4, h = p & 15;
  const float* row = Kc + ((size_t)(b * 1024 + c)) * 1024 + h * 64;
  double s = 0.0;
  for (int d = 0; d < 64; ++d) { double v = (double)row[d]; s += v * v; }
  kn[(size_t)p * 1024 + c] = 1.0 / fmax(sqrt(s), 1e-12);
}

// Fused exact top-64 + softmax + PV (bit-frozen). SPLITOUT: write at as
// separate hi/lo bf16 planes (identical values to Wo's in-kernel split).
template <bool SPLITOUT>
__global__ __launch_bounds__(256) void topk_attn_k(
    const double* __restrict__ dotb, const double* __restrict__ kn,
    const float* __restrict__ Vc, float* __restrict__ atF,
    short* __restrict__ atHi, short* __restrict__ atLo, int group_base)
{
  __shared__ int sC[4][64];
  __shared__ float sD[4][64];

  const int lane = threadIdx.x & 63, wv = threadIdx.x >> 6;
  const int g = (int)blockIdx.x >> 8;
  const int t = ((int)blockIdx.x & 255) * 4 + wv;
  const int pair = group_base + g;
  const int bb = pair >> 4, hh = pair & 15;

  const double* drow = dotb + ((size_t)g * Tn + t) * (size_t)Cn;
  const double* knr  = kn + ((size_t)(bb * Hn + hh)) * Cn;

  double dv[16];
  unsigned long long u[16];
#pragma unroll
  for (int j = 0; j < 8; ++j) {
    double2 dd = *(const double2*)(drow + j * 128 + 2 * lane);
    double2 kk = *(const double2*)(knr  + j * 128 + 2 * lane);
    dv[2 * j] = dd.x; dv[2 * j + 1] = dd.y;
    u[2 * j]     = mapd(dd.x * kk.x);
    u[2 * j + 1] = mapd(dd.y * kk.y);
  }
  unsigned hi[16];
#pragma unroll
  for (int i = 0; i < 16; ++i) hi[i] = (unsigned)(u[i] >> 32);

  unsigned TH = 0;
  for (int bit = 31; bit >= 0; --bit) {
    unsigned Tc = TH | (1u << bit);
    int c = 0;
#pragma unroll
    for (int i = 0; i < 16; ++i) c += (hi[i] >= Tc);
    if (wsumi(c) >= 64) TH = Tc;
  }
  int mhi = 0;
#pragma unroll
  for (int i = 0; i < 16; ++i) mhi += (hi[i] > TH);
  mhi = wsumi(mhi);
  const int need1 = 64 - mhi;
  unsigned TL = 0;
  for (int bit = 31; bit >= 0; --bit) {
    unsigned Tc = TL | (1u << bit);
    int c = 0;
#pragma unroll
    for (int i = 0; i < 16; ++i) c += (hi[i] == TH && (unsigned)u[i] >= Tc);
    if (wsumi(c) >= need1) TL = Tc;
  }
  const unsigned long long V64 = ((unsigned long long)TH << 32) | TL;

  int base = 0;
#pragma unroll
  for (int i = 0; i < 16; ++i) {
    const int cix = 128 * (i >> 1) + 2 * lane + (i & 1);
    bool sel = (u[i] > V64);
    unsigned long long mk = __ballot(sel);
    if (sel) {
      int r = __popcll(mk & ((1ull << lane) - 1ull));
      sC[wv][base + r] = cix;
      sD[wv][base + r] = (float)dv[i];
    }
    base += __popcll(mk);
  }
  const int need = 64 - base;
  unsigned taken = 0;
  for (int r = 0; r < need; ++r) {
    int mn = 0x7fffffff;
#pragma unroll
    for (int i = 0; i < 16; ++i) {
      int cix = 128 * (i >> 1) + 2 * lane + (i & 1);
      if (u[i] == V64 && !((taken >> i) & 1u)) mn = mn < cix ? mn : cix;
    }
    mn = wmini(mn);
#pragma unroll
    for (int i = 0; i < 16; ++i) {
      int cix = 128 * (i >> 1) + 2 * lane + (i & 1);
      if (u[i] == V64 && !((taken >> i) & 1u) && cix == mn) {
        taken |= 1u << i;
        sC[wv][base + r] = mn;
        sD[wv][base + r] = (float)dv[i];
      }
    }
  }
  __syncthreads();

  int ck = sC[wv][lane];
  float sc = sD[wv][lane] * 0.125f;
  float mx = wfmax(sc);
  float w = expf(sc - mx);
  float sw = wfsum(w);
  w /= sw;

  const float* Vb = Vc + (size_t)bb * ((size_t)Cn * 1024) + hh * 64 + lane;
  float acc = 0.f;
#pragma unroll 4
  for (int k = 0; k < 64; ++k) {
    int c = __shfl(ck, k);
    float wk = __shfl(w, k);
    acc = fmaf(wk, Vb[(size_t)c * 1024], acc);
  }
  size_t o = ((size_t)(bb * Tn + t)) * 1024 + hh * 64 + lane;
  if (SPLITOUT) {
    BfPair p = split2(acc);
    atHi[o] = p.hi;
    atLo[o] = p.lo;
  } else {
    atF[o] = acc;
  }
}

// ---------------------------------------------------------------------------
extern "C" void kernel_launch(void* const* d_in, const int* in_sizes, int n_in,
                              void* d_out, int out_size, void* d_ws, size_t ws_size,
                              hipStream_t stream)
{
  const float* x  = (const float*)d_in[0];
  const float* Wq = (const float*)d_in[1];
  const float* bq = (const float*)d_in[2];
  const float* Wk = (const float*)d_in[3];
  const float* bk = (const float*)d_in[4];
  const float* Wv = (const float*)d_in[5];
  const float* bv = (const float*)d_in[6];
  const float* Wo = (const float*)d_in[7];
  const float* bo = (const float*)d_in[8];
  const float* Wc = (const float*)d_in[9];
  const float* bc = (const float*)d_in[10];
  float* out = (float*)d_out;

  const size_t NE = (size_t)2048 * 1024;   // elems per 2048x1024 plane
  const size_t M1 = (size_t)1024 * 1024;
  float* Q   = (float*)d_ws;               // slot0 [0,8)MiB
  float* Kf  = Q + NE;                     // slot1 [8,16)  -> dotp lo half
  float* Vf  = Kf + NE;                    // slot2 [16,24) -> dotp hi half
  float* Kc  = Vf + NE;                    // slot3 [24,32)
  float* Vc  = Kc + NE;                    // slot4 [32,40)
  float* at  = Vc + NE;                    // slot5 [40,48): xsplit then atsplit
  double* kn = (double*)(at + NE);         // 256 KiB
  short* Wsp = (short*)(kn + 32768);       // 4 MiB: W hi|lo (tier-A only)
  double* tail = (double*)(Wsp + 2 * M1);  // tier-A tail

  short* xhi = (short*)at;                 // x split planes (dead after Vproj)
  short* xlo = xhi + NE;
  short* athi = (short*)at;                // at split planes (from topk on)
  short* atlo = athi + NE;
  short* Whi = Wsp;
  short* Wlo = Wsp + M1;

  const size_t fixedB = 6 * NE * 4 + 32768 * 8;         // 48.25 MiB
  const size_t dotPairB = (size_t)Tn * Cn * 8;          // 8 MiB per pair
  if (ws_size < fixedB) return;
  const bool TA = ws_size >= fixedB + ((size_t)1 << 22);  // +4MiB for Wsp

  dim3 blk(256, 1, 1);

  // ---- selection-path projections (frozen) ----
  gemm_k<float, double, true, 1, false><<<dim3(16, 32, 1), blk, 0, stream>>>(
      x, Wq, bq, Q, 1024, 1024, 1024, 1024, 0, 0, 0, 0);
  gemm_k<float, double, true, 1, false><<<dim3(16, 32, 1), blk, 0, stream>>>(
      x, Wk, bk, Kf, 1024, 1024, 1024, 1024, 0, 0, 0, 0);

  // ---- V projection ----
  if (TA) {
    presplit2_k<<<dim3(1024), blk, 0, stream>>>(x, xhi, xlo, (int)(NE / 8));
    presplit2_k<<<dim3(512), blk, 0, stream>>>(Wv, Whi, Wlo, (int)(M1 / 8));
    bfgemm_k<<<dim3(16, 32, 1), blk, 0, stream>>>(
        xhi, xlo, Whi, Wlo, bv, Vf, 1024, 1024, 1024, 1024);
  } else {
    mfma_gemm_k<true, 1><<<dim3(16, 32, 1), blk, 0, stream>>>(
        x, Wv, bv, Vf, 1024, 1024, 1024, 1024, 0, 0);
  }

  // ---- compress ----
  gemm_k<float, double, false, 2, false><<<dim3(16, 16, 2), blk, 0, stream>>>(
      Wc, Kf, bc, Kc, 1024, 1024, 1024, 1024, 0, (long long)M1, (long long)M1, 0);
  mfma_gemm_k<false, 2><<<dim3(16, 16, 2), blk, 0, stream>>>(
      Wc, Vf, bc, Vc, 1024, 1024, 1024, 1024, (long long)M1, (long long)M1);

  kn_k2<<<dim3(128), blk, 0, stream>>>(Kc, kn);

  // ---- dot planes + fused topk/softmax/PV ----
  size_t tailOff = TA ? (fixedB + ((size_t)1 << 22)) : fixedB;
  size_t rem = ws_size - tailOff;
  double* dotp; int G;
  double* tl = TA ? tail : (double*)((char*)d_ws + fixedB);
  if      (rem >= 8 * dotPairB) { G = 8; dotp = tl; }
  else if (rem >= 4 * dotPairB) { G = 4; dotp = tl; }
  else if (rem >= 2 * dotPairB) { G = 2; dotp = tl; }
  else { G = 2; dotp = (double*)Kf; }  // Kf+Vf dead by now (16 MiB)

  for (int gb = 0; gb < 32; gb += G) {
    gemm_k<double, double, true, 0, true><<<dim3(16, 16, G), blk, 0, stream>>>(
        Q, Kc, nullptr, dotp, 64, 1024, 1024, 1024, 0, 0, 0, gb);
    if (TA)
      topk_attn_k<true><<<dim3(256 * G), blk, 0, stream>>>(
          dotp, kn, Vc, nullptr, athi, atlo, gb);
    else
      topk_attn_k<false><<<dim3(256 * G), blk, 0, stream>>>(
          dotp, kn, Vc, at, nullptr, nullptr, gb);
  }

  // ---- output projection ----
  if (TA) {
    presplit2_k<<<dim3(512), blk, 0, stream>>>(Wo, Whi, Wlo, (int)(M1 / 8));
    bfgemm_k<<<dim3(16, 32, 1), blk, 0, stream>>>(
        athi, atlo, Whi, Wlo, bo, out, 1024, 1024, 1024, 1024);
  } else {
    mfma_gemm_k<true, 1><<<dim3(16, 32, 1), blk, 0, stream>>>(
        at, Wo, bo, out, 1024, 1024, 1024, 1024, 0, 0);
  }
}

// Round 12
// 882.164 us; speedup vs baseline: 1.5332x; 1.0892x over previous
//
#include <hip/hip_runtime.h>
#include <type_traits>

// ---------------------------------------------------------------------------
// CSAAttention — round 12.
//   Selection path: Q, K, Kc, dots via f64-MFMA with RUNTIME LAYOUT PROBE
//   (v_mfma_f64_16x16x4). Probe determines the D mapping among 4 candidates;
//   if none matches, in-kernel scalar fp64 fallback (bit-identical to the
//   frozen gemm_k chains). fp64-order changes are selection-safe (~1e-16).
//   Value path (V, Vc, Wo), topk, kn: round-11 verbatim.
// ---------------------------------------------------------------------------

#define DEVI __device__ __forceinline__

constexpr int Tn = 1024;
constexpr int Cn = 1024;
constexpr int Hn = 16;

typedef short bf16x8 __attribute__((ext_vector_type(8)));
typedef float f32x4 __attribute__((ext_vector_type(4)));
typedef double f64x4 __attribute__((ext_vector_type(4)));

DEVI int wsumi(int v)   { for (int m = 1; m < 64; m <<= 1) v += __shfl_xor(v, m); return v; }
DEVI int wmini(int v)   { for (int m = 1; m < 64; m <<= 1) { int o = __shfl_xor(v, m); v = o < v ? o : v; } return v; }
DEVI float wfmax(float v){ for (int m = 1; m < 64; m <<= 1) v = fmaxf(v, __shfl_xor(v, m)); return v; }
DEVI float wfsum(float v){ for (int m = 1; m < 64; m <<= 1) v += __shfl_xor(v, m); return v; }

DEVI unsigned long long mapd(double x) {  // monotone fp64 -> uint64
  unsigned long long b = (unsigned long long)__double_as_longlong(x);
  return (b >> 63) ? ~b : (b | 0x8000000000000000ull);
}

DEVI unsigned short f2bf_rne(float x) {
  unsigned u = __float_as_uint(x);
  u += 0x7fffu + ((u >> 16) & 1u);
  return (unsigned short)(u >> 16);
}
struct BfPair { short hi, lo; };
DEVI BfPair split2(float x) {
  unsigned short h = f2bf_rne(x);
  float hf = __uint_as_float(((unsigned)h) << 16);
  BfPair r;
  r.hi = (short)h;
  r.lo = (short)f2bf_rne(x - hf);
  return r;
}

// ---------------------------------------------------------------------------
// Selection-path fp64 GEMM with probed f64-MFMA (scalar fp64 fallback).
// C = A * op(B) (+bias). Tile 64x64, 4 waves (2x2 of 32x32), BK=16.
// BTRANS: B[N][K]. BIASMODE: 0 none, 1 bias[n], 2 bias[m].
// SIM: per-z (b,h) slices of Q/Kc -> fp64 dot plane.
// ---------------------------------------------------------------------------
template <typename OUTT, bool BTRANS, int BIASMODE, bool SIM>
__global__ __launch_bounds__(256) void f64sel_k(
    const float* __restrict__ A, const float* __restrict__ B,
    const float* __restrict__ bias, OUTT* __restrict__ C,
    int Kd, int lda, int ldb, int ldc,
    long long zB, long long zC, int group_base)
{
  __shared__ float As[16][68];
  __shared__ float Bs[16][68];

  size_t offA = 0, offB = 0, offC = 0;
  if (SIM) {
    int pair = group_base + (int)blockIdx.z;
    int bb = pair >> 4, hh = pair & 15;
    offA = ((size_t)bb * Tn) * (size_t)lda + (size_t)hh * 64;
    offB = ((size_t)bb * Cn) * (size_t)ldb + (size_t)hh * 64;
    offC = (size_t)blockIdx.z * (size_t)Tn * (size_t)ldc;
  } else {
    offB = (size_t)blockIdx.z * (size_t)zB;
    offC = (size_t)blockIdx.z * (size_t)zC;
  }
  const float* Ab = A + offA;
  const float* Bb = B + offB;
  OUTT* Cb = C + offC;

  const int tid = threadIdx.x;
  const int lane = tid & 63, w = tid >> 6;
  const int wr = w >> 1, wc = w & 1;
  const int l15 = lane & 15, l4 = lane >> 4;
  const int m0 = blockIdx.y * 64, n0 = blockIdx.x * 64;

  // ---- runtime layout probe (wave-uniform) ----
  // P1: A = all-ones (mapping-independent), B[k][j] = j  => D[i][j] = 4j
  // P2: A[i][k] = i, B = all-ones                        => D[i][j] = 4i
  f64x4 zz = {0.0, 0.0, 0.0, 0.0};
  f64x4 p1 = __builtin_amdgcn_mfma_f64_16x16x4f64(1.0, (double)l15, zz, 0, 0, 0);
  f64x4 p2 = __builtin_amdgcn_mfma_f64_16x16x4f64((double)l15, 1.0, zz, 0, 0, 0);
  int a1 = 1, b1 = 1, c1 = 1, a2 = 1, b2 = 1, c2 = 1;
#pragma unroll
  for (int rr = 0; rr < 4; ++rr) {
    a1 &= (p1[rr] == 4.0 * l15);
    b1 &= (p1[rr] == 4.0 * (l4 * 4 + rr));
    c1 &= (p1[rr] == 4.0 * (l4 + 4 * rr));
    a2 &= (p2[rr] == 4.0 * (l4 * 4 + rr));
    b2 &= (p2[rr] == 4.0 * (l4 + 4 * rr));
    c2 &= (p2[rr] == 4.0 * l15);
  }
  a1 = __all(a1); b1 = __all(b1); c1 = __all(c1);
  a2 = __all(a2); b2 = __all(b2); c2 = __all(c2);
  int dmap = 0, useM = 1;
  if      (a1 && a2) dmap = 0;       // col=l15, row=(l>>4)*4+rr  (blocked)
  else if (a1 && b2) dmap = 1;       // col=l15, row=(l>>4)+4*rr  (strided)
  else if (b1 && c2) dmap = 2;       // transposed-blocked
  else if (c1 && c2) dmap = 3;       // transposed-strided
  else useM = 0;                     // unknown mapping -> scalar fallback

  f64x4 acc[2][2];
#pragma unroll
  for (int i = 0; i < 2; ++i)
#pragma unroll
    for (int j = 0; j < 2; ++j) acc[i][j] = (f64x4){0.0, 0.0, 0.0, 0.0};

  for (int k0 = 0; k0 < Kd; k0 += 16) {
    {  // stage A: 64 rows x 16 k -> As[k][m]  (identical to frozen gemm_k)
      int m = tid >> 2, kf = tid & 3;
      float4 a = *(const float4*)(Ab + (size_t)(m0 + m) * lda + k0 + 4 * kf);
      As[4 * kf + 0][m] = a.x; As[4 * kf + 1][m] = a.y;
      As[4 * kf + 2][m] = a.z; As[4 * kf + 3][m] = a.w;
    }
    if (BTRANS) {
      int n = tid >> 2, kf = tid & 3;
      float4 b = *(const float4*)(Bb + (size_t)(n0 + n) * ldb + k0 + 4 * kf);
      Bs[4 * kf + 0][n] = b.x; Bs[4 * kf + 1][n] = b.y;
      Bs[4 * kf + 2][n] = b.z; Bs[4 * kf + 3][n] = b.w;
    } else {
      int k = tid >> 4, nf = tid & 15;
      float4 b = *(const float4*)(Bb + (size_t)(k0 + k) * ldb + n0 + 4 * nf);
      *(float4*)&Bs[k][4 * nf] = b;
    }
    __syncthreads();

    if (useM) {
#pragma unroll
      for (int kq = 0; kq < 4; ++kq) {
        int kk = kq * 4 + l4;
        double a0  = (double)As[kk][wr * 32 + l15];
        double a1v = (double)As[kk][wr * 32 + 16 + l15];
        double b0  = (double)Bs[kk][wc * 32 + l15];
        double b1v = (double)Bs[kk][wc * 32 + 16 + l15];
        acc[0][0] = __builtin_amdgcn_mfma_f64_16x16x4f64(a0,  b0,  acc[0][0], 0, 0, 0);
        acc[0][1] = __builtin_amdgcn_mfma_f64_16x16x4f64(a0,  b1v, acc[0][1], 0, 0, 0);
        acc[1][0] = __builtin_amdgcn_mfma_f64_16x16x4f64(a1v, b0,  acc[1][0], 0, 0, 0);
        acc[1][1] = __builtin_amdgcn_mfma_f64_16x16x4f64(a1v, b1v, acc[1][1], 0, 0, 0);
      }
    } else {
      // scalar fp64 fallback: same per-element product sequence as the
      // frozen gemm_k (ascending k) -> bit-identical outputs (dmap0 index)
#pragma unroll
      for (int k = 0; k < 16; ++k) {
        double bv0 = (double)Bs[k][wc * 32 + l15];
        double bv1 = (double)Bs[k][wc * 32 + 16 + l15];
#pragma unroll
        for (int fr = 0; fr < 2; ++fr)
#pragma unroll
          for (int rr = 0; rr < 4; ++rr) {
            double av = (double)As[k][wr * 32 + fr * 16 + l4 * 4 + rr];
            acc[fr][0][rr] += av * bv0;
            acc[fr][1][rr] += av * bv1;
          }
      }
    }
    __syncthreads();
  }

  // epilogue (frozen formula: fp64->fp32 cast, then fp32 bias adds)
#pragma unroll
  for (int fr = 0; fr < 2; ++fr)
#pragma unroll
    for (int fc = 0; fc < 2; ++fc)
#pragma unroll
      for (int rr = 0; rr < 4; ++rr) {
        int ri, ci;
        if (!useM || dmap == 0) { ri = l4 * 4 + rr; ci = l15; }
        else if (dmap == 1)     { ri = l4 + 4 * rr; ci = l15; }
        else if (dmap == 2)     { ri = l15; ci = l4 * 4 + rr; }
        else                    { ri = l15; ci = l4 + 4 * rr; }
        int row = m0 + wr * 32 + fr * 16 + ri;
        int col = n0 + wc * 32 + fc * 16 + ci;
        double v = acc[fr][fc][rr];
        if constexpr (std::is_same<OUTT, double>::value) {
          Cb[(size_t)row * ldc + col] = v;
        } else {
          float s = (float)v;
          float cb = (BIASMODE == 1) ? bias[col] : 0.f;
          float rb = (BIASMODE == 2) ? bias[row] : 0.f;
          ((float*)Cb)[(size_t)row * ldc + col] = s + cb + rb;
        }
      }
}

// ---------------------------------------------------------------------------
// presplit2: fp32 plane -> two separate bf16 planes (hi, lo). n8 = n/8.
// ---------------------------------------------------------------------------
__global__ __launch_bounds__(256) void presplit2_k(
    const float* __restrict__ src, short* __restrict__ hi,
    short* __restrict__ lo, int n8)
{
  int stride = (int)gridDim.x * 256;
  for (int i = (int)blockIdx.x * 256 + (int)threadIdx.x; i < n8; i += stride) {
    float4 v0 = ((const float4*)src)[2 * i];
    float4 v1 = ((const float4*)src)[2 * i + 1];
    BfPair q0 = split2(v0.x), q1 = split2(v0.y), q2 = split2(v0.z), q3 = split2(v0.w);
    BfPair q4 = split2(v1.x), q5 = split2(v1.y), q6 = split2(v1.z), q7 = split2(v1.w);
    bf16x8 h = {q0.hi, q1.hi, q2.hi, q3.hi, q4.hi, q5.hi, q6.hi, q7.hi};
    bf16x8 l = {q0.lo, q1.lo, q2.lo, q3.lo, q4.lo, q5.lo, q6.lo, q7.lo};
    ((bf16x8*)hi)[i] = h;
    ((bf16x8*)lo)[i] = l;
  }
}

// ---------------------------------------------------------------------------
// Pure-bf16-staging MFMA GEMM: C = A * B^T + bias[n], fp32 out. (R11)
// ---------------------------------------------------------------------------
__global__ __launch_bounds__(256) void bfgemm_k(
    const short* __restrict__ Ahi, const short* __restrict__ Alo,
    const short* __restrict__ Bhi, const short* __restrict__ Blo,
    const float* __restrict__ bias, float* __restrict__ C,
    int Kd, int lda, int ldb, int ldc)
{
  __shared__ short Ah[4 * 64 * 8];
  __shared__ short Al[4 * 64 * 8];
  __shared__ short Bh[4 * 64 * 8];
  __shared__ short Bl[4 * 64 * 8];

  const int tid = threadIdx.x;
  const int lane = tid & 63, w = tid >> 6;
  const int wr = w >> 1, wc = w & 1;
  const int m0 = blockIdx.y * 64, n0 = blockIdx.x * 64;
  const int r16 = lane & 15, kg = lane >> 4;

  f32x4 acc[2][2];
#pragma unroll
  for (int i = 0; i < 2; ++i)
#pragma unroll
    for (int j = 0; j < 2; ++j) acc[i][j] = (f32x4){0.f, 0.f, 0.f, 0.f};

  const int row = tid >> 2, kseg = tid & 3;
  const int sidx = (kseg * 64 + row) * 8;

  for (int k0 = 0; k0 < Kd; k0 += 32) {
    size_t ao = (size_t)(m0 + row) * lda + k0 + kseg * 8;
    size_t bo = (size_t)(n0 + row) * ldb + k0 + kseg * 8;
    *(bf16x8*)&Ah[sidx] = *(const bf16x8*)(Ahi + ao);
    *(bf16x8*)&Al[sidx] = *(const bf16x8*)(Alo + ao);
    *(bf16x8*)&Bh[sidx] = *(const bf16x8*)(Bhi + bo);
    *(bf16x8*)&Bl[sidx] = *(const bf16x8*)(Blo + bo);
    __syncthreads();

    bf16x8 ah[2], al[2], bh[2], bl[2];
#pragma unroll
    for (int f = 0; f < 2; ++f) {
      int ia = (kg * 64 + wr * 32 + f * 16 + r16) * 8;
      int ib = (kg * 64 + wc * 32 + f * 16 + r16) * 8;
      ah[f] = *(const bf16x8*)&Ah[ia];
      al[f] = *(const bf16x8*)&Al[ia];
      bh[f] = *(const bf16x8*)&Bh[ib];
      bl[f] = *(const bf16x8*)&Bl[ib];
    }
#pragma unroll
    for (int fr = 0; fr < 2; ++fr)
#pragma unroll
      for (int fc = 0; fc < 2; ++fc) {
        f32x4 c = acc[fr][fc];
        c = __builtin_amdgcn_mfma_f32_16x16x32_bf16(al[fr], bh[fc], c, 0, 0, 0);
        c = __builtin_amdgcn_mfma_f32_16x16x32_bf16(ah[fr], bl[fc], c, 0, 0, 0);
        c = __builtin_amdgcn_mfma_f32_16x16x32_bf16(ah[fr], bh[fc], c, 0, 0, 0);
        acc[fr][fc] = c;
      }
    __syncthreads();
  }

#pragma unroll
  for (int fr = 0; fr < 2; ++fr)
#pragma unroll
    for (int fc = 0; fc < 2; ++fc) {
      int col = n0 + wc * 32 + fc * 16 + r16;
      float cb = bias[col];
#pragma unroll
      for (int rr = 0; rr < 4; ++rr) {
        int rw = m0 + wr * 32 + fr * 16 + kg * 4 + rr;
        C[(size_t)rw * ldc + col] = acc[fr][fc][rr] + cb;
      }
    }
}

// ---------------------------------------------------------------------------
// Value-path MFMA GEMM, split-in-kernel (R9-validated) — Vc + tier-B.
// ---------------------------------------------------------------------------
template <bool BTRANS, int BIASMODE>
__global__ __launch_bounds__(256) void mfma_gemm_k(
    const float* __restrict__ A, const float* __restrict__ B,
    const float* __restrict__ bias, float* __restrict__ C,
    int Kd, int lda, int ldb, int ldc, long long zB, long long zC)
{
  __shared__ short Ah[4 * 64 * 8];
  __shared__ short Al[4 * 64 * 8];
  __shared__ short Bh[4 * 64 * 8];
  __shared__ short Bl[4 * 64 * 8];

  const float* Bz = B + (size_t)blockIdx.z * (size_t)zB;
  float* Cz = C + (size_t)blockIdx.z * (size_t)zC;

  const int tid = threadIdx.x;
  const int lane = tid & 63, w = tid >> 6;
  const int wr = w >> 1, wc = w & 1;
  const int m0 = blockIdx.y * 64, n0 = blockIdx.x * 64;
  const int r16 = lane & 15, kg = lane >> 4;

  f32x4 acc[2][2];
#pragma unroll
  for (int i = 0; i < 2; ++i)
#pragma unroll
    for (int j = 0; j < 2; ++j) acc[i][j] = (f32x4){0.f, 0.f, 0.f, 0.f};

  for (int k0 = 0; k0 < Kd; k0 += 32) {
    {
      int row = tid >> 2, kseg = tid & 3;
      const float* p = A + (size_t)(m0 + row) * lda + k0 + kseg * 8;
      float4 v0 = *(const float4*)p;
      float4 v1 = *(const float4*)(p + 4);
      BfPair q0 = split2(v0.x), q1 = split2(v0.y), q2 = split2(v0.z), q3 = split2(v0.w);
      BfPair q4 = split2(v1.x), q5 = split2(v1.y), q6 = split2(v1.z), q7 = split2(v1.w);
      bf16x8 h = {q0.hi, q1.hi, q2.hi, q3.hi, q4.hi, q5.hi, q6.hi, q7.hi};
      bf16x8 l = {q0.lo, q1.lo, q2.lo, q3.lo, q4.lo, q5.lo, q6.lo, q7.lo};
      int idx = (kseg * 64 + row) * 8;
      *(bf16x8*)&Ah[idx] = h;
      *(bf16x8*)&Al[idx] = l;
    }
    if (BTRANS) {
      int row = tid >> 2, kseg = tid & 3;
      const float* p = Bz + (size_t)(n0 + row) * ldb + k0 + kseg * 8;
      float4 v0 = *(const float4*)p;
      float4 v1 = *(const float4*)(p + 4);
      BfPair q0 = split2(v0.x), q1 = split2(v0.y), q2 = split2(v0.z), q3 = split2(v0.w);
      BfPair q4 = split2(v1.x), q5 = split2(v1.y), q6 = split2(v1.z), q7 = split2(v1.w);
      bf16x8 h = {q0.hi, q1.hi, q2.hi, q3.hi, q4.hi, q5.hi, q6.hi, q7.hi};
      bf16x8 l = {q0.lo, q1.lo, q2.lo, q3.lo, q4.lo, q5.lo, q6.lo, q7.lo};
      int idx = (kseg * 64 + row) * 8;
      *(bf16x8*)&Bh[idx] = h;
      *(bf16x8*)&Bl[idx] = l;
    } else {
      int col = tid & 63, kseg = tid >> 6;
      short hv[8], lv[8];
#pragma unroll
      for (int j = 0; j < 8; ++j) {
        BfPair p = split2(Bz[(size_t)(k0 + kseg * 8 + j) * ldb + n0 + col]);
        hv[j] = p.hi; lv[j] = p.lo;
      }
      bf16x8 h = {hv[0], hv[1], hv[2], hv[3], hv[4], hv[5], hv[6], hv[7]};
      bf16x8 l = {lv[0], lv[1], lv[2], lv[3], lv[4], lv[5], lv[6], lv[7]};
      int idx = (kseg * 64 + col) * 8;
      *(bf16x8*)&Bh[idx] = h;
      *(bf16x8*)&Bl[idx] = l;
    }
    __syncthreads();

    bf16x8 ah[2], al[2], bh[2], bl[2];
#pragma unroll
    for (int f = 0; f < 2; ++f) {
      int ia = (kg * 64 + wr * 32 + f * 16 + r16) * 8;
      int ib = (kg * 64 + wc * 32 + f * 16 + r16) * 8;
      ah[f] = *(const bf16x8*)&Ah[ia];
      al[f] = *(const bf16x8*)&Al[ia];
      bh[f] = *(const bf16x8*)&Bh[ib];
      bl[f] = *(const bf16x8*)&Bl[ib];
    }
#pragma unroll
    for (int fr = 0; fr < 2; ++fr)
#pragma unroll
      for (int fc = 0; fc < 2; ++fc) {
        f32x4 c = acc[fr][fc];
        c = __builtin_amdgcn_mfma_f32_16x16x32_bf16(al[fr], bh[fc], c, 0, 0, 0);
        c = __builtin_amdgcn_mfma_f32_16x16x32_bf16(ah[fr], bl[fc], c, 0, 0, 0);
        c = __builtin_amdgcn_mfma_f32_16x16x32_bf16(ah[fr], bh[fc], c, 0, 0, 0);
        acc[fr][fc] = c;
      }
    __syncthreads();
  }

#pragma unroll
  for (int fr = 0; fr < 2; ++fr)
#pragma unroll
    for (int fc = 0; fc < 2; ++fc) {
      int col = n0 + wc * 32 + fc * 16 + r16;
      float cb = (BIASMODE == 1) ? bias[col] : 0.f;
#pragma unroll
      for (int rr = 0; rr < 4; ++rr) {
        int rw = m0 + wr * 32 + fr * 16 + kg * 4 + rr;
        float rb = (BIASMODE == 2) ? bias[rw] : 0.f;
        Cz[(size_t)rw * ldc + col] = acc[fr][fc][rr] + cb + rb;
      }
    }
}

// kn[b*16+h][c] = 1 / max(||Kc[b, c, h*64 : +64]||, 1e-12)   (fp64)
__global__ __launch_bounds__(256) void kn_k2(const float* __restrict__ Kc,
                                             double* __restrict__ kn)
{
  int idx = (int)blockIdx.x * 256 + (int)threadIdx.x;
  int c = idx & 1023;
  int p = idx >> 10;
  int b = p >> 4, h = p & 15;
  const float* row = Kc + ((size_t)(b * 1024 + c)) * 1024 + h * 64;
  double s = 0.0;
  for (int d = 0; d < 64; ++d) { double v = (double)row[d]; s += v * v; }
  kn[(size_t)p * 1024 + c] = 1.0 / fmax(sqrt(s), 1e-12);
}

// Fused exact top-64 + softmax + PV (bit-frozen). SPLITOUT: at as hi/lo bf16.
template <bool SPLITOUT>
__global__ __launch_bounds__(256) void topk_attn_k(
    const double* __restrict__ dotb, const double* __restrict__ kn,
    const float* __restrict__ Vc, float* __restrict__ atF,
    short* __restrict__ atHi, short* __restrict__ atLo, int group_base)
{
  __shared__ int sC[4][64];
  __shared__ float sD[4][64];

  const int lane = threadIdx.x & 63, wv = threadIdx.x >> 6;
  const int g = (int)blockIdx.x >> 8;
  const int t = ((int)blockIdx.x & 255) * 4 + wv;
  const int pair = group_base + g;
  const int bb = pair >> 4, hh = pair & 15;

  const double* drow = dotb + ((size_t)g * Tn + t) * (size_t)Cn;
  const double* knr  = kn + ((size_t)(bb * Hn + hh)) * Cn;

  double dv[16];
  unsigned long long u[16];
#pragma unroll
  for (int j = 0; j < 8; ++j) {
    double2 dd = *(const double2*)(drow + j * 128 + 2 * lane);
    double2 kk = *(const double2*)(knr  + j * 128 + 2 * lane);
    dv[2 * j] = dd.x; dv[2 * j + 1] = dd.y;
    u[2 * j]     = mapd(dd.x * kk.x);
    u[2 * j + 1] = mapd(dd.y * kk.y);
  }
  unsigned hi[16];
#pragma unroll
  for (int i = 0; i < 16; ++i) hi[i] = (unsigned)(u[i] >> 32);

  unsigned TH = 0;
  for (int bit = 31; bit >= 0; --bit) {
    unsigned Tc = TH | (1u << bit);
    int c = 0;
#pragma unroll
    for (int i = 0; i < 16; ++i) c += (hi[i] >= Tc);
    if (wsumi(c) >= 64) TH = Tc;
  }
  int mhi = 0;
#pragma unroll
  for (int i = 0; i < 16; ++i) mhi += (hi[i] > TH);
  mhi = wsumi(mhi);
  const int need1 = 64 - mhi;
  unsigned TL = 0;
  for (int bit = 31; bit >= 0; --bit) {
    unsigned Tc = TL | (1u << bit);
    int c = 0;
#pragma unroll
    for (int i = 0; i < 16; ++i) c += (hi[i] == TH && (unsigned)u[i] >= Tc);
    if (wsumi(c) >= need1) TL = Tc;
  }
  const unsigned long long V64 = ((unsigned long long)TH << 32) | TL;

  int base = 0;
#pragma unroll
  for (int i = 0; i < 16; ++i) {
    const int cix = 128 * (i >> 1) + 2 * lane + (i & 1);
    bool sel = (u[i] > V64);
    unsigned long long mk = __ballot(sel);
    if (sel) {
      int r = __popcll(mk & ((1ull << lane) - 1ull));
      sC[wv][base + r] = cix;
      sD[wv][base + r] = (float)dv[i];
    }
    base += __popcll(mk);
  }
  const int need = 64 - base;
  unsigned taken = 0;
  for (int r = 0; r < need; ++r) {
    int mn = 0x7fffffff;
#pragma unroll
    for (int i = 0; i < 16; ++i) {
      int cix = 128 * (i >> 1) + 2 * lane + (i & 1);
      if (u[i] == V64 && !((taken >> i) & 1u)) mn = mn < cix ? mn : cix;
    }
    mn = wmini(mn);
#pragma unroll
    for (int i = 0; i < 16; ++i) {
      int cix = 128 * (i >> 1) + 2 * lane + (i & 1);
      if (u[i] == V64 && !((taken >> i) & 1u) && cix == mn) {
        taken |= 1u << i;
        sC[wv][base + r] = mn;
        sD[wv][base + r] = (float)dv[i];
      }
    }
  }
  __syncthreads();

  int ck = sC[wv][lane];
  float sc = sD[wv][lane] * 0.125f;
  float mx = wfmax(sc);
  float w = expf(sc - mx);
  float sw = wfsum(w);
  w /= sw;

  const float* Vb = Vc + (size_t)bb * ((size_t)Cn * 1024) + hh * 64 + lane;
  float acc = 0.f;
#pragma unroll 4
  for (int k = 0; k < 64; ++k) {
    int c = __shfl(ck, k);
    float wk = __shfl(w, k);
    acc = fmaf(wk, Vb[(size_t)c * 1024], acc);
  }
  size_t o = ((size_t)(bb * Tn + t)) * 1024 + hh * 64 + lane;
  if (SPLITOUT) {
    BfPair p = split2(acc);
    atHi[o] = p.hi;
    atLo[o] = p.lo;
  } else {
    atF[o] = acc;
  }
}

// ---------------------------------------------------------------------------
extern "C" void kernel_launch(void* const* d_in, const int* in_sizes, int n_in,
                              void* d_out, int out_size, void* d_ws, size_t ws_size,
                              hipStream_t stream)
{
  const float* x  = (const float*)d_in[0];
  const float* Wq = (const float*)d_in[1];
  const float* bq = (const float*)d_in[2];
  const float* Wk = (const float*)d_in[3];
  const float* bk = (const float*)d_in[4];
  const float* Wv = (const float*)d_in[5];
  const float* bv = (const float*)d_in[6];
  const float* Wo = (const float*)d_in[7];
  const float* bo = (const float*)d_in[8];
  const float* Wc = (const float*)d_in[9];
  const float* bc = (const float*)d_in[10];
  float* out = (float*)d_out;

  const size_t NE = (size_t)2048 * 1024;
  const size_t M1 = (size_t)1024 * 1024;
  float* Q   = (float*)d_ws;
  float* Kf  = Q + NE;
  float* Vf  = Kf + NE;
  float* Kc  = Vf + NE;
  float* Vc  = Kc + NE;
  float* at  = Vc + NE;
  double* kn = (double*)(at + NE);
  short* Wsp = (short*)(kn + 32768);       // 4 MiB (tier-A)
  double* tail = (double*)(Wsp + 2 * M1);

  short* xhi = (short*)at;
  short* xlo = xhi + NE;
  short* athi = (short*)at;
  short* atlo = athi + NE;
  short* Whi = Wsp;
  short* Wlo = Wsp + M1;

  const size_t fixedB = 6 * NE * 4 + 32768 * 8;
  const size_t dotPairB = (size_t)Tn * Cn * 8;
  if (ws_size < fixedB) return;
  const bool TA = ws_size >= fixedB + ((size_t)1 << 22);

  dim3 blk(256, 1, 1);

  // ---- selection-path projections (probed f64-MFMA / scalar fallback) ----
  f64sel_k<float, true, 1, false><<<dim3(16, 32, 1), blk, 0, stream>>>(
      x, Wq, bq, Q, 1024, 1024, 1024, 1024, 0, 0, 0);
  f64sel_k<float, true, 1, false><<<dim3(16, 32, 1), blk, 0, stream>>>(
      x, Wk, bk, Kf, 1024, 1024, 1024, 1024, 0, 0, 0);

  // ---- V projection ----
  if (TA) {
    presplit2_k<<<dim3(1024), blk, 0, stream>>>(x, xhi, xlo, (int)(NE / 8));
    presplit2_k<<<dim3(512), blk, 0, stream>>>(Wv, Whi, Wlo, (int)(M1 / 8));
    bfgemm_k<<<dim3(16, 32, 1), blk, 0, stream>>>(
        xhi, xlo, Whi, Wlo, bv, Vf, 1024, 1024, 1024, 1024);
  } else {
    mfma_gemm_k<true, 1><<<dim3(16, 32, 1), blk, 0, stream>>>(
        x, Wv, bv, Vf, 1024, 1024, 1024, 1024, 0, 0);
  }

  // ---- compress ----
  f64sel_k<float, false, 2, false><<<dim3(16, 16, 2), blk, 0, stream>>>(
      Wc, Kf, bc, Kc, 1024, 1024, 1024, 1024, (long long)M1, (long long)M1, 0);
  mfma_gemm_k<false, 2><<<dim3(16, 16, 2), blk, 0, stream>>>(
      Wc, Vf, bc, Vc, 1024, 1024, 1024, 1024, (long long)M1, (long long)M1);

  kn_k2<<<dim3(128), blk, 0, stream>>>(Kc, kn);

  // ---- dot planes + fused topk/softmax/PV ----
  size_t tailOff = TA ? (fixedB + ((size_t)1 << 22)) : fixedB;
  size_t rem = ws_size - tailOff;
  double* dotp; int G;
  double* tl = TA ? tail : (double*)((char*)d_ws + fixedB);
  if      (rem >= 8 * dotPairB) { G = 8; dotp = tl; }
  else if (rem >= 4 * dotPairB) { G = 4; dotp = tl; }
  else if (rem >= 2 * dotPairB) { G = 2; dotp = tl; }
  else { G = 2; dotp = (double*)Kf; }  // Kf+Vf dead by now

  for (int gb = 0; gb < 32; gb += G) {
    f64sel_k<double, true, 0, true><<<dim3(16, 16, G), blk, 0, stream>>>(
        Q, Kc, nullptr, dotp, 64, 1024, 1024, 1024, 0, 0, gb);
    if (TA)
      topk_attn_k<true><<<dim3(256 * G), blk, 0, stream>>>(
          dotp, kn, Vc, nullptr, athi, atlo, gb);
    else
      topk_attn_k<false><<<dim3(256 * G), blk, 0, stream>>>(
          dotp, kn, Vc, at, nullptr, nullptr, gb);
  }

  // ---- output projection ----
  if (TA) {
    presplit2_k<<<dim3(512), blk, 0, stream>>>(Wo, Whi, Wlo, (int)(M1 / 8));
    bfgemm_k<<<dim3(16, 32, 1), blk, 0, stream>>>(
        athi, atlo, Whi, Wlo, bo, out, 1024, 1024, 1024, 1024);
  } else {
    mfma_gemm_k<true, 1><<<dim3(16, 32, 1), blk, 0, stream>>>(
        at, Wo, bo, out, 1024, 1024, 1024, 1024, 0, 0);
  }
}